// Round 13
// baseline (3493.299 us; speedup 1.0000x reference)
//
#include <hip/hip_runtime.h>
#include <math.h>

// SPD Karcher mean, B=256 x N=64 SPD 32x32.
// R13: (1) apq one-hot fold tree-split (4 chains of 8 + 3 adds): cuts the
// per-round serial fma chain 128->~45 cy; perturbs only rotation ANGLES by
// ~1 ulp (not the data path — R11's lesson), so absmax stays ~0.03125.
// (2) kern_reduce fused into kern_stepfuse (same ps order + same symmetrize
// expression -> bit-identical dataflow); 6 fewer launches, no T round-trip.
// Else identical to R12: XOR Jacobi, packed col phase w/ pinned contraction,
// SW_ACC=2, SW_MEAN=4, ITERS=6, kern_acc NG=16 dyn-LDS, prep/stepfuse NG=4.

#define B_     256
#define N_     64
#define DD     32
#define LDM    36           // LDS stride for matmul staging (16B-aligned rows)
#define EPS_   1e-6f
#define NG     4            // groups per block (prep/stepfuse)
#define NT     (NG*32)
#define ACC_NG 16           // groups per block (kern_acc)
#define ACC_NT (ACC_NG*32)  // 512 threads
#define SW_ACC  2
#define SW_MEAN 4
#define ITERS  6
#define PARTS  (N_/ACC_NG)  // 4 acc-blocks per batch element

typedef float v2f __attribute__((ext_vector_type(2)));
#define AE(i) a[(i)>>1][(i)&1]
#define VE(i) v[(i)>>1][(i)&1]

__device__ __forceinline__ void wsync() { __builtin_amdgcn_wave_barrier(); }

__device__ __forceinline__ float fast_rcp(float x)  { float r; asm("v_rcp_f32 %0, %1"  : "=v"(r) : "v"(x)); return r; }
__device__ __forceinline__ float fast_rsq(float x)  { float r; asm("v_rsq_f32 %0, %1"  : "=v"(r) : "v"(x)); return r; }
__device__ __forceinline__ float fast_sqrt(float x) { float r; asm("v_sqrt_f32 %0, %1" : "=v"(r) : "v"(x)); return r; }

// ---------------------------------------------------------------------------
// xmove<M>: y[lane] = x[lane ^ M] within each 32-lane group (M in 1..31).
// M<=15: DPP compositions; M>=16: ds_swizzle BitMode (new_lane = lane ^ M).
// ---------------------------------------------------------------------------
template<int CTRL> __device__ __forceinline__ int dppmov(int x) {
  return __builtin_amdgcn_mov_dpp(x, CTRL, 0xF, 0xF, true);
}
template<int M> __device__ __forceinline__ float xmove(float xf) {
  int x = __float_as_int(xf);
  if constexpr (M >= 16) {
    x = __builtin_amdgcn_ds_swizzle(x, (M << 10) | 0x1F);
  } else if constexpr (M == 1)  { x = dppmov<0xB1>(x); }
  else if constexpr (M == 2)  { x = dppmov<0x4E>(x); }
  else if constexpr (M == 3)  { x = dppmov<0x1B>(x); }
  else if constexpr (M == 4)  { x = dppmov<0x141>(x); x = dppmov<0x1B>(x); }
  else if constexpr (M == 5)  { x = dppmov<0x141>(x); x = dppmov<0x4E>(x); }
  else if constexpr (M == 6)  { x = dppmov<0x141>(x); x = dppmov<0xB1>(x); }
  else if constexpr (M == 7)  { x = dppmov<0x141>(x); }
  else if constexpr (M == 8)  { x = dppmov<0x140>(x); x = dppmov<0x141>(x); }
  else if constexpr (M == 9)  { x = dppmov<0x140>(x); x = dppmov<0x141>(x); x = dppmov<0xB1>(x); }
  else if constexpr (M == 10) { x = dppmov<0x140>(x); x = dppmov<0x141>(x); x = dppmov<0x4E>(x); }
  else if constexpr (M == 11) { x = dppmov<0x140>(x); x = dppmov<0x141>(x); x = dppmov<0x1B>(x); }
  else if constexpr (M == 12) { x = dppmov<0x140>(x); x = dppmov<0x1B>(x); }
  else if constexpr (M == 13) { x = dppmov<0x140>(x); x = dppmov<0x4E>(x); }
  else if constexpr (M == 14) { x = dppmov<0x140>(x); x = dppmov<0xB1>(x); }
  else if constexpr (M == 15) { x = dppmov<0x140>(x); }
  return __int_as_float(x);
}

__host__ __device__ constexpr int HBIT(int m) {
  return (m >= 16) ? 16 : (m >= 8) ? 8 : (m >= 4) ? 4 : (m >= 2) ? 2 : 1;
}

// ---------------------------------------------------------------------------
// One XOR-Jacobi round, mask M. AE(i)=A[i][lt] (column lt), ind one-hot at lt.
// ---------------------------------------------------------------------------
template<int M>
__device__ __forceinline__ void jround(v2f a[DD/2], v2f v[DD/2],
                                       const float ind[DD], float& dg,
                                       float* __restrict__ cs, const int lt)
{
  constexpr int HB = HBIT(M);
  const bool isp = ((lt & HB) == 0);

  // apq = A[lt^M][lt]: one-hot fold, tree-split into 4 chains (latency).
  float p0 = 0.f, p1 = 0.f, p2 = 0.f, p3 = 0.f;
  #pragma unroll
  for (int j = 0; j < DD; j += 4) {
    const int j0 = (j+0) ^ M, j1 = (j+1) ^ M, j2 = (j+2) ^ M, j3 = (j+3) ^ M;
    p0 = fmaf(ind[j+0], a[j0 >> 1][j0 & 1], p0);
    p1 = fmaf(ind[j+1], a[j1 >> 1][j1 & 1], p1);
    p2 = fmaf(ind[j+2], a[j2 >> 1][j2 & 1], p2);
    p3 = fmaf(ind[j+3], a[j3 >> 1][j3 & 1], p3);
  }
  float apq = (p0 + p1) + (p2 + p3);
  const float apq_sw = xmove<M>(apq);
  apq = isp ? apq : apq_sw;

  const float dq  = xmove<M>(dg);
  const float app = isp ? dg : dq;
  const float aqq = isp ? dq : dg;
  const bool  act = (fabsf(apq) > 1e-36f);
  const float tau = (aqq - app) * 0.5f * fast_rcp(act ? apq : 1.0f);
  float t = copysignf(fast_rcp(fabsf(tau) + fast_sqrt(fmaf(tau, tau, 1.0f))), tau);
  t = act ? t : 0.0f;
  const float c = fast_rsq(fmaf(t, t, 1.0f));
  const float s = t * c;
  const float ssgn = isp ? -s : s;
  const float tsgn = isp ? -t : t;

  wsync();
  cs[lt] = isp ? c : s;
  wsync();
  float crs[DD];
  #pragma unroll
  for (int j = 0; j < 8; ++j) {
    const float4 q4 = *(const float4*)(cs + 4*j);
    crs[4*j+0] = q4.x; crs[4*j+1] = q4.y; crs[4*j+2] = q4.z; crs[4*j+3] = q4.w;
  }
  wsync();

  // row phase (J^T A): static register pairs (i, i^M)
  #pragma unroll
  for (int i = 0; i < DD; ++i) {
    if ((i & HB) == 0) {
      const int j = i ^ M;
      const float ck = crs[i], sk = crs[j];
      const float x0 = a[i >> 1][i & 1], x1 = a[j >> 1][j & 1];
      a[i >> 1][i & 1] = ck*x0 - sk*x1;
      a[j >> 1][j & 1] = sk*x0 + ck*x1;
    }
  }
  // col phase (A J, V J): packed update, contraction pinned (R12):
  // per component fma(ssgn, partner, round(c*own)) — cc*a stays a pk_mul.
  const v2f cc = {c, c};
  const v2f sg = {ssgn, ssgn};
  #pragma unroll
  for (int i2 = 0; i2 < DD/2; ++i2) {
    v2f am; am.x = xmove<M>(a[i2].x); am.y = xmove<M>(a[i2].y);
    a[i2] = __builtin_elementwise_fma(sg, am, cc*a[i2]);
    v2f vm; vm.x = xmove<M>(v[i2].x); vm.y = xmove<M>(v[i2].y);
    v[i2] = __builtin_elementwise_fma(sg, vm, cc*v[i2]);
  }
  dg = fmaf(tsgn, apq, dg);
}

template<int M>
__device__ __forceinline__ void jsweep(v2f a[DD/2], v2f v[DD/2],
                                       const float ind[DD], float& dg,
                                       float* __restrict__ cs, const int lt)
{
  jround<M>(a, v, ind, dg, cs, lt);
  if constexpr (M < 31) jsweep<M+1>(a, v, ind, dg, cs, lt);
}

template<int NSW>
__device__ __forceinline__ void jacobi_xor(v2f a[DD/2], v2f v[DD/2],
                                           const float ind[DD], float& dg,
                                           float* __restrict__ cs, const int lt)
{
  #pragma unroll
  for (int i2 = 0; i2 < DD/2; ++i2) {
    v2f iv; iv.x = (2*i2 == lt) ? 1.0f : 0.0f; iv.y = (2*i2+1 == lt) ? 1.0f : 0.0f;
    v[i2] = iv;
  }
  for (int sw = 0; sw < NSW; ++sw)
    jsweep<1>(a, v, ind, dg, cs, lt);
}

// ---------------------------------------------------------------------------
// X0 = sum_n (w_n/sum w) P[b][n]; block 0 also writes wnorm[n] = w_n/sum w
// ---------------------------------------------------------------------------
__global__ __launch_bounds__(256) void kern_x0(const float* __restrict__ P,
                                               const float* __restrict__ w,
                                               float* __restrict__ X,
                                               float* __restrict__ wnorm)
{
  const int b = blockIdx.x;
  const int t = threadIdx.x;
  float wsum = 0.0f;
  for (int n = 0; n < N_; ++n) wsum += w[n];
  const float inv = 1.0f / wsum;
  float4 acc = make_float4(0.f, 0.f, 0.f, 0.f);
  for (int n = 0; n < N_; ++n) {
    const float wn = w[n] * inv;
    const float4 p = *(const float4*)(P + ((size_t)(b*N_ + n))*DD*DD + t*4);
    acc.x += wn*p.x; acc.y += wn*p.y; acc.z += wn*p.z; acc.w += wn*p.w;
  }
  *(float4*)(X + (size_t)b*DD*DD + t*4) = acc;
  if (b == 0 && t < N_) wnorm[t] = w[t] * inv;
}

// ---------------------------------------------------------------------------
// prep: eigh(X) -> sq = X^{1/2}, isq = X^{-1/2}
// ---------------------------------------------------------------------------
__global__ __launch_bounds__(NT) void kern_prep(const float* __restrict__ Xin,
                                                float* __restrict__ sq,
                                                float* __restrict__ isq)
{
  __shared__ __align__(16) float S1a[NG][DD*LDM];
  __shared__ __align__(16) float csa[NG][DD];
  __shared__ __align__(16) float e0a[NG][DD];
  __shared__ __align__(16) float e1a[NG][DD];

  const int g  = threadIdx.x >> 5;
  const int lt = threadIdx.x & 31;
  const int b  = blockIdx.x * NG + g;
  float* S1 = S1a[g];

  float ind_[DD];
  #pragma unroll
  for (int i = 0; i < DD; ++i) ind_[i] = (i == lt) ? 1.0f : 0.0f;

  v2f a[DD/2], v[DD/2];
  float dg = 0.f;
  #pragma unroll
  for (int i = 0; i < DD; ++i) {
    const float val = Xin[(size_t)b*DD*DD + i*DD + lt];
    AE(i) = val;
    dg = fmaf(ind_[i], val, dg);
  }
  jacobi_xor<SW_MEAN>(a, v, ind_, dg, csa[g], lt);

  const float se = fast_sqrt(fmaxf(dg, EPS_));
  e0a[g][lt] = se;
  e1a[g][lt] = fast_rcp(se);
  #pragma unroll
  for (int i = 0; i < DD; ++i) S1[i*LDM + lt] = VE(i);
  wsync();

  float w1[DD], w2[DD];
  #pragma unroll
  for (int j = 0; j < 8; ++j) {
    const float4 vr = *(const float4*)(S1 + lt*LDM + 4*j);
    const float4 q0 = *(const float4*)(e0a[g] + 4*j);
    const float4 q1 = *(const float4*)(e1a[g] + 4*j);
    w1[4*j+0]=vr.x*q0.x; w1[4*j+1]=vr.y*q0.y; w1[4*j+2]=vr.z*q0.z; w1[4*j+3]=vr.w*q0.w;
    w2[4*j+0]=vr.x*q1.x; w2[4*j+1]=vr.y*q1.y; w2[4*j+2]=vr.z*q1.z; w2[4*j+3]=vr.w*q1.w;
  }
  #pragma unroll
  for (int i = 0; i < DD; ++i) {
    float a1 = 0.f, a2 = 0.f;
    #pragma unroll
    for (int j = 0; j < 8; ++j) {
      const float4 vk = *(const float4*)(S1 + i*LDM + 4*j);
      a1 += vk.x*w1[4*j+0] + vk.y*w1[4*j+1] + vk.z*w1[4*j+2] + vk.w*w1[4*j+3];
      a2 += vk.x*w2[4*j+0] + vk.y*w2[4*j+1] + vk.z*w2[4*j+2] + vk.w*w2[4*j+3];
    }
    sq [(size_t)b*DD*DD + i*DD + lt] = a1;
    isq[(size_t)b*DD*DD + i*DD + lt] = a2;
  }
}

// ---------------------------------------------------------------------------
// acc (NG=16, dynamic LDS): M = isq P isq (sym), eigh(M), L = V log(e) V^T,
// partial T -> part. LDS layout: qsh | S1a[16] | csa[16] (lga aliases csa).
// ---------------------------------------------------------------------------
__global__ __launch_bounds__(ACC_NT) void kern_acc(const float* __restrict__ P,
                                                   const float* __restrict__ wnorm,
                                                   const float* __restrict__ isq,
                                                   float* __restrict__ part)
{
  extern __shared__ __align__(16) float smem[];
  float* qsh = smem;                               // DD*LDM floats
  float* S1a = smem + DD*LDM;                      // ACC_NG * DD*LDM
  float* csa = S1a + (size_t)ACC_NG*DD*LDM;        // ACC_NG * DD

  const int g  = threadIdx.x >> 5;
  const int lt = threadIdx.x & 31;
  const int b  = blockIdx.x / PARTS;
  const int n  = (blockIdx.x % PARTS) * ACC_NG + g;
  float* S1 = S1a + (size_t)g*DD*LDM;
  float* cs = csa + g*DD;                          // also lga after jacobi

  for (int e = threadIdx.x; e < DD*DD; e += ACC_NT)
    qsh[(e >> 5)*LDM + (e & 31)] = isq[(size_t)b*DD*DD + e];

  const float* Pn = P + ((size_t)(b*N_ + n))*DD*DD;
  #pragma unroll
  for (int i = 0; i < DD; ++i) S1[i*LDM + lt] = Pn[i*DD + lt];  // stage P rows
  __syncthreads();

  float ind_[DD];
  #pragma unroll
  for (int i = 0; i < DD; ++i) ind_[i] = (i == lt) ? 1.0f : 0.0f;

  float qc[DD];                                   // isq column lt
  #pragma unroll
  for (int k = 0; k < DD; ++k) qc[k] = qsh[k*LDM + lt];
  // u = P * qc
  float u[DD];
  #pragma unroll
  for (int i = 0; i < DD; ++i) {
    float acc = 0.f;
    #pragma unroll
    for (int j = 0; j < 8; ++j) {
      const float4 pr = *(const float4*)(S1 + i*LDM + 4*j);
      acc += pr.x*qc[4*j+0] + pr.y*qc[4*j+1] + pr.z*qc[4*j+2] + pr.w*qc[4*j+3];
    }
    u[i] = acc;
  }
  // m-col = isq * u (= column lt of M)
  float mm[DD];
  #pragma unroll
  for (int i = 0; i < DD; ++i) {
    float acc = 0.f;
    #pragma unroll
    for (int j = 0; j < 8; ++j) {
      const float4 qr = *(const float4*)(qsh + i*LDM + 4*j);
      acc += qr.x*u[4*j+0] + qr.y*u[4*j+1] + qr.z*u[4*j+2] + qr.w*u[4*j+3];
    }
    mm[i] = acc;
  }
  // symmetrize via S1 (P no longer needed)
  wsync();
  #pragma unroll
  for (int i = 0; i < DD; ++i) S1[i*LDM + lt] = mm[i];
  wsync();
  v2f a[DD/2], v[DD/2];
  float dg = 0.f;
  #pragma unroll
  for (int i = 0; i < DD; ++i) {
    const float val = 0.5f*(mm[i] + S1[lt*LDM + i]);
    AE(i) = val;
    dg = fmaf(ind_[i], val, dg);
  }

  jacobi_xor<SW_ACC>(a, v, ind_, dg, cs, lt);

  cs[lt] = logf(fmaxf(dg, EPS_));   // lga aliased onto csa (jacobi done)
  wsync();
  #pragma unroll
  for (int i = 0; i < DD; ++i) S1[i*LDM + lt] = VE(i);   // spill V
  wsync();

  float wl[DD];
  #pragma unroll
  for (int j = 0; j < 8; ++j) {
    const float4 vr = *(const float4*)(S1 + lt*LDM + 4*j);
    const float4 l4 = *(const float4*)(cs + 4*j);
    wl[4*j+0]=vr.x*l4.x; wl[4*j+1]=vr.y*l4.y; wl[4*j+2]=vr.z*l4.z; wl[4*j+3]=vr.w*l4.w;
  }
  float tc[DD];
  #pragma unroll
  for (int i = 0; i < DD; ++i) {
    float acc = 0.f;
    #pragma unroll
    for (int j = 0; j < 8; ++j) {
      const float4 vk = *(const float4*)(S1 + i*LDM + 4*j);
      acc += vk.x*wl[4*j+0] + vk.y*wl[4*j+1] + vk.z*wl[4*j+2] + vk.w*wl[4*j+3];
    }
    tc[i] = acc;
  }
  const float wn = wnorm[n];
  wsync();
  #pragma unroll
  for (int i = 0; i < DD; ++i) S1[i*LDM + lt] = wn * tc[i];
  __syncthreads();
  // deterministic per-block partial (16 groups summed)
  for (int e = threadIdx.x; e < DD*DD; e += ACC_NT) {
    float ssum = 0.f;
    #pragma unroll
    for (int gg = 0; gg < ACC_NG; ++gg) ssum += S1a[(size_t)gg*DD*LDM + (e >> 5)*LDM + (e & 31)];
    part[(size_t)blockIdx.x*DD*DD + e] = ssum;
  }
}

// ---------------------------------------------------------------------------
// stepfuse (reduce fused): T = sym(sum_ps part), eigh(T), E=V exp(e) V^T,
// Xn = sq E sq (sym); then fused prep: eigh(Xn) -> sq', isq'.
// Last iteration writes Xn to out instead.
// ---------------------------------------------------------------------------
__global__ __launch_bounds__(NT) void kern_stepfuse(const float* __restrict__ part,
                                                    float* __restrict__ sq,
                                                    float* __restrict__ isq,
                                                    float* __restrict__ out,
                                                    const int last)
{
  __shared__ __align__(16) float S1a[NG][DD*LDM];
  __shared__ __align__(16) float S2a[NG][DD*LDM];
  __shared__ __align__(16) float csa[NG][DD];
  __shared__ __align__(16) float e0a[NG][DD];
  __shared__ __align__(16) float e1a[NG][DD];

  const int g  = threadIdx.x >> 5;
  const int lt = threadIdx.x & 31;
  const int b  = blockIdx.x * NG + g;
  float* S1 = S1a[g]; float* S2 = S2a[g];

  float ind_[DD];
  #pragma unroll
  for (int i = 0; i < DD; ++i) ind_[i] = (i == lt) ? 1.0f : 0.0f;

  // --- fused reduce: S = sum_ps part[b*PARTS+ps]; T = 0.5*(S + S^T) ---
  v2f a[DD/2], v[DD/2];
  float sr[DD];
  #pragma unroll
  for (int i = 0; i < DD; ++i) {
    float s = 0.f;
    #pragma unroll
    for (int ps = 0; ps < PARTS; ++ps)
      s += part[((size_t)(b*PARTS + ps))*DD*DD + i*DD + lt];
    sr[i] = s;
    S1[i*LDM + lt] = s;
  }
  wsync();
  float dg = 0.f;
  #pragma unroll
  for (int i = 0; i < DD; ++i) {
    const float val = 0.5f*(sr[i] + S1[lt*LDM + i]);
    AE(i) = val;
    dg = fmaf(ind_[i], val, dg);
  }
  jacobi_xor<SW_MEAN>(a, v, ind_, dg, csa[g], lt);

  // E = V exp(d) V^T, column lt
  e0a[g][lt] = expf(dg);
  #pragma unroll
  for (int i = 0; i < DD; ++i) S1[i*LDM + lt] = VE(i);
  wsync();
  float wl[DD];
  #pragma unroll
  for (int j = 0; j < 8; ++j) {
    const float4 vr = *(const float4*)(S1 + lt*LDM + 4*j);
    const float4 ee = *(const float4*)(e0a[g] + 4*j);
    wl[4*j+0]=vr.x*ee.x; wl[4*j+1]=vr.y*ee.y; wl[4*j+2]=vr.z*ee.z; wl[4*j+3]=vr.w*ee.w;
  }
  float ec[DD];
  #pragma unroll
  for (int i = 0; i < DD; ++i) {
    float acc = 0.f;
    #pragma unroll
    for (int j = 0; j < 8; ++j) {
      const float4 vk = *(const float4*)(S1 + i*LDM + 4*j);
      acc += vk.x*wl[4*j+0] + vk.y*wl[4*j+1] + vk.z*wl[4*j+2] + vk.w*wl[4*j+3];
    }
    ec[i] = acc;
  }
  // stage sq rows (S2) + own column (sqc)
  float sqc[DD];
  #pragma unroll
  for (int i = 0; i < DD; ++i) {
    sqc[i] = sq[(size_t)b*DD*DD + i*DD + lt];
    S2[i*LDM + lt] = sqc[i];
  }
  wsync();
  #pragma unroll
  for (int i = 0; i < DD; ++i) S1[i*LDM + lt] = ec[i];  // E columns (V dead)
  wsync();
  // h = E * sqc
  float h[DD];
  #pragma unroll
  for (int i = 0; i < DD; ++i) {
    float acc = 0.f;
    #pragma unroll
    for (int j = 0; j < 8; ++j) {
      const float4 er = *(const float4*)(S1 + i*LDM + 4*j);
      acc += er.x*sqc[4*j+0] + er.y*sqc[4*j+1] + er.z*sqc[4*j+2] + er.w*sqc[4*j+3];
    }
    h[i] = acc;
  }
  // xn = sq * h
  float xn[DD];
  #pragma unroll
  for (int i = 0; i < DD; ++i) {
    float acc = 0.f;
    #pragma unroll
    for (int j = 0; j < 8; ++j) {
      const float4 srd = *(const float4*)(S2 + i*LDM + 4*j);
      acc += srd.x*h[4*j+0] + srd.y*h[4*j+1] + srd.z*h[4*j+2] + srd.w*h[4*j+3];
    }
    xn[i] = acc;
  }
  // symmetrize Xn via S1
  wsync();
  #pragma unroll
  for (int i = 0; i < DD; ++i) S1[i*LDM + lt] = xn[i];
  wsync();
  dg = 0.f;
  #pragma unroll
  for (int i = 0; i < DD; ++i) {
    const float val = 0.5f*(xn[i] + S1[lt*LDM + i]);
    AE(i) = val;
    dg = fmaf(ind_[i], val, dg);
  }

  if (last) {
    #pragma unroll
    for (int i = 0; i < DD; ++i) out[(size_t)b*DD*DD + i*DD + lt] = AE(i);
    return;
  }

  // fused prep: eigh(Xn) -> sq', isq'
  jacobi_xor<SW_MEAN>(a, v, ind_, dg, csa[g], lt);
  const float se = fast_sqrt(fmaxf(dg, EPS_));
  e0a[g][lt] = se;
  e1a[g][lt] = fast_rcp(se);
  wsync();
  #pragma unroll
  for (int i = 0; i < DD; ++i) S1[i*LDM + lt] = VE(i);
  wsync();
  float w1[DD], w2[DD];
  #pragma unroll
  for (int j = 0; j < 8; ++j) {
    const float4 vr = *(const float4*)(S1 + lt*LDM + 4*j);
    const float4 q0 = *(const float4*)(e0a[g] + 4*j);
    const float4 q1 = *(const float4*)(e1a[g] + 4*j);
    w1[4*j+0]=vr.x*q0.x; w1[4*j+1]=vr.y*q0.y; w1[4*j+2]=vr.z*q0.z; w1[4*j+3]=vr.w*q0.w;
    w2[4*j+0]=vr.x*q1.x; w2[4*j+1]=vr.y*q1.y; w2[4*j+2]=vr.z*q1.z; w2[4*j+3]=vr.w*q1.w;
  }
  #pragma unroll
  for (int i = 0; i < DD; ++i) {
    float a1 = 0.f, a2 = 0.f;
    #pragma unroll
    for (int j = 0; j < 8; ++j) {
      const float4 vk = *(const float4*)(S1 + i*LDM + 4*j);
      a1 += vk.x*w1[4*j+0] + vk.y*w1[4*j+1] + vk.z*w1[4*j+2] + vk.w*w1[4*j+3];
      a2 += vk.x*w2[4*j+0] + vk.y*w2[4*j+1] + vk.z*w2[4*j+2] + vk.w*w2[4*j+3];
    }
    sq [(size_t)b*DD*DD + i*DD + lt] = a1;
    isq[(size_t)b*DD*DD + i*DD + lt] = a2;
  }
}

// ---------------------------------------------------------------------------
extern "C" void kernel_launch(void* const* d_in, const int* in_sizes, int n_in,
                              void* d_out, int out_size, void* d_ws, size_t ws_size,
                              hipStream_t stream)
{
  (void)in_sizes; (void)n_in; (void)out_size; (void)ws_size;
  const float* P = (const float*)d_in[0];   // [B][N][32][32] f32
  const float* w = (const float*)d_in[1];   // [N] f32
  float* out   = (float*)d_out;
  float* X0    = (float*)d_ws;                                  // 1 MB (x0->prep)
  float* sq    = X0  + (size_t)B_*DD*DD;                        // 1 MB
  float* isq   = sq  + (size_t)B_*DD*DD;                        // 1 MB
  float* part  = isq + (size_t)B_*DD*DD;                        // 4 MB
  float* wnorm = part + (size_t)B_*PARTS*DD*DD;                 // 256 B

  const size_t acc_lds = (size_t)(DD*LDM*(1 + ACC_NG) + ACC_NG*DD) * sizeof(float); // 80384 B

  kern_x0<<<B_, 256, 0, stream>>>(P, w, X0, wnorm);
  kern_prep<<<B_/NG, NT, 0, stream>>>(X0, sq, isq);
  for (int it = 0; it < ITERS; ++it) {
    kern_acc     <<<B_*PARTS, ACC_NT, acc_lds, stream>>>(P, wnorm, isq, part);
    kern_stepfuse<<<B_/NG,    NT,     0,       stream>>>(part, sq, isq, out, (it == ITERS-1) ? 1 : 0);
  }
}

// Round 14
// 3343.615 us; speedup vs baseline: 1.0448x; 1.0448x over previous
//
#include <hip/hip_runtime.h>
#include <math.h>

// SPD Karcher mean, B=256 x N=64 SPD 32x32.
// R14 = exact R12 rollback (measured best: 3.34 ms, absmax 0.03125).
// R13's apq tree-split regressed kern_acc 396->417us (compiler rescheduling
// beat the hand latency-split) and the reduce fusion was neutral-negative
// (moved work into the 64-block latency-bound stepfuse). Both reverted.
// XOR Jacobi, packed col phase w/ pinned contraction, SW_ACC=2, SW_MEAN=4,
// ITERS=6, kern_acc NG=16 dyn-LDS (16 waves/CU), prep/stepfuse NG=4.

#define B_     256
#define N_     64
#define DD     32
#define LDM    36           // LDS stride for matmul staging (16B-aligned rows)
#define LDD    33           // LDS stride for reduce tile
#define EPS_   1e-6f
#define NG     4            // groups per block (prep/stepfuse)
#define NT     (NG*32)
#define ACC_NG 16           // groups per block (kern_acc)
#define ACC_NT (ACC_NG*32)  // 512 threads
#define SW_ACC  2
#define SW_MEAN 4
#define ITERS  6
#define PARTS  (N_/ACC_NG)  // 4 acc-blocks per batch element

typedef float v2f __attribute__((ext_vector_type(2)));
#define AE(i) a[(i)>>1][(i)&1]
#define VE(i) v[(i)>>1][(i)&1]

__device__ __forceinline__ void wsync() { __builtin_amdgcn_wave_barrier(); }

__device__ __forceinline__ float fast_rcp(float x)  { float r; asm("v_rcp_f32 %0, %1"  : "=v"(r) : "v"(x)); return r; }
__device__ __forceinline__ float fast_rsq(float x)  { float r; asm("v_rsq_f32 %0, %1"  : "=v"(r) : "v"(x)); return r; }
__device__ __forceinline__ float fast_sqrt(float x) { float r; asm("v_sqrt_f32 %0, %1" : "=v"(r) : "v"(x)); return r; }

// ---------------------------------------------------------------------------
// xmove<M>: y[lane] = x[lane ^ M] within each 32-lane group (M in 1..31).
// M<=15: DPP compositions; M>=16: ds_swizzle BitMode (new_lane = lane ^ M).
// ---------------------------------------------------------------------------
template<int CTRL> __device__ __forceinline__ int dppmov(int x) {
  return __builtin_amdgcn_mov_dpp(x, CTRL, 0xF, 0xF, true);
}
template<int M> __device__ __forceinline__ float xmove(float xf) {
  int x = __float_as_int(xf);
  if constexpr (M >= 16) {
    x = __builtin_amdgcn_ds_swizzle(x, (M << 10) | 0x1F);
  } else if constexpr (M == 1)  { x = dppmov<0xB1>(x); }
  else if constexpr (M == 2)  { x = dppmov<0x4E>(x); }
  else if constexpr (M == 3)  { x = dppmov<0x1B>(x); }
  else if constexpr (M == 4)  { x = dppmov<0x141>(x); x = dppmov<0x1B>(x); }
  else if constexpr (M == 5)  { x = dppmov<0x141>(x); x = dppmov<0x4E>(x); }
  else if constexpr (M == 6)  { x = dppmov<0x141>(x); x = dppmov<0xB1>(x); }
  else if constexpr (M == 7)  { x = dppmov<0x141>(x); }
  else if constexpr (M == 8)  { x = dppmov<0x140>(x); x = dppmov<0x141>(x); }
  else if constexpr (M == 9)  { x = dppmov<0x140>(x); x = dppmov<0x141>(x); x = dppmov<0xB1>(x); }
  else if constexpr (M == 10) { x = dppmov<0x140>(x); x = dppmov<0x141>(x); x = dppmov<0x4E>(x); }
  else if constexpr (M == 11) { x = dppmov<0x140>(x); x = dppmov<0x141>(x); x = dppmov<0x1B>(x); }
  else if constexpr (M == 12) { x = dppmov<0x140>(x); x = dppmov<0x1B>(x); }
  else if constexpr (M == 13) { x = dppmov<0x140>(x); x = dppmov<0x4E>(x); }
  else if constexpr (M == 14) { x = dppmov<0x140>(x); x = dppmov<0xB1>(x); }
  else if constexpr (M == 15) { x = dppmov<0x140>(x); }
  return __int_as_float(x);
}

__host__ __device__ constexpr int HBIT(int m) {
  return (m >= 16) ? 16 : (m >= 8) ? 8 : (m >= 4) ? 4 : (m >= 2) ? 2 : 1;
}

// ---------------------------------------------------------------------------
// One XOR-Jacobi round, mask M. AE(i)=A[i][lt] (column lt), ind one-hot at lt.
// ---------------------------------------------------------------------------
template<int M>
__device__ __forceinline__ void jround(v2f a[DD/2], v2f v[DD/2],
                                       const float ind[DD], float& dg,
                                       float* __restrict__ cs, const int lt)
{
  constexpr int HB = HBIT(M);
  const bool isp = ((lt & HB) == 0);

  float apq = 0.0f;
  #pragma unroll
  for (int j = 0; j < DD; ++j) {
    const int jm = j ^ M;
    apq = fmaf(ind[j], a[jm >> 1][jm & 1], apq);
  }
  const float apq_sw = xmove<M>(apq);
  apq = isp ? apq : apq_sw;

  const float dq  = xmove<M>(dg);
  const float app = isp ? dg : dq;
  const float aqq = isp ? dq : dg;
  const bool  act = (fabsf(apq) > 1e-36f);
  const float tau = (aqq - app) * 0.5f * fast_rcp(act ? apq : 1.0f);
  float t = copysignf(fast_rcp(fabsf(tau) + fast_sqrt(fmaf(tau, tau, 1.0f))), tau);
  t = act ? t : 0.0f;
  const float c = fast_rsq(fmaf(t, t, 1.0f));
  const float s = t * c;
  const float ssgn = isp ? -s : s;
  const float tsgn = isp ? -t : t;

  wsync();
  cs[lt] = isp ? c : s;
  wsync();
  float crs[DD];
  #pragma unroll
  for (int j = 0; j < 8; ++j) {
    const float4 q4 = *(const float4*)(cs + 4*j);
    crs[4*j+0] = q4.x; crs[4*j+1] = q4.y; crs[4*j+2] = q4.z; crs[4*j+3] = q4.w;
  }
  wsync();

  // row phase (J^T A): static register pairs (i, i^M)
  #pragma unroll
  for (int i = 0; i < DD; ++i) {
    if ((i & HB) == 0) {
      const int j = i ^ M;
      const float ck = crs[i], sk = crs[j];
      const float x0 = a[i >> 1][i & 1], x1 = a[j >> 1][j & 1];
      a[i >> 1][i & 1] = ck*x0 - sk*x1;
      a[j >> 1][j & 1] = sk*x0 + ck*x1;
    }
  }
  // col phase (A J, V J): packed update, contraction pinned to match R10:
  // per component fma(ssgn, partner, round(c*own)) — cc*a stays a pk_mul.
  const v2f cc = {c, c};
  const v2f sg = {ssgn, ssgn};
  #pragma unroll
  for (int i2 = 0; i2 < DD/2; ++i2) {
    v2f am; am.x = xmove<M>(a[i2].x); am.y = xmove<M>(a[i2].y);
    a[i2] = __builtin_elementwise_fma(sg, am, cc*a[i2]);
    v2f vm; vm.x = xmove<M>(v[i2].x); vm.y = xmove<M>(v[i2].y);
    v[i2] = __builtin_elementwise_fma(sg, vm, cc*v[i2]);
  }
  dg = fmaf(tsgn, apq, dg);
}

template<int M>
__device__ __forceinline__ void jsweep(v2f a[DD/2], v2f v[DD/2],
                                       const float ind[DD], float& dg,
                                       float* __restrict__ cs, const int lt)
{
  jround<M>(a, v, ind, dg, cs, lt);
  if constexpr (M < 31) jsweep<M+1>(a, v, ind, dg, cs, lt);
}

template<int NSW>
__device__ __forceinline__ void jacobi_xor(v2f a[DD/2], v2f v[DD/2],
                                           const float ind[DD], float& dg,
                                           float* __restrict__ cs, const int lt)
{
  #pragma unroll
  for (int i2 = 0; i2 < DD/2; ++i2) {
    v2f iv; iv.x = (2*i2 == lt) ? 1.0f : 0.0f; iv.y = (2*i2+1 == lt) ? 1.0f : 0.0f;
    v[i2] = iv;
  }
  for (int sw = 0; sw < NSW; ++sw)
    jsweep<1>(a, v, ind, dg, cs, lt);
}

// ---------------------------------------------------------------------------
// X0 = sum_n (w_n/sum w) P[b][n]; block 0 also writes wnorm[n] = w_n/sum w
// ---------------------------------------------------------------------------
__global__ __launch_bounds__(256) void kern_x0(const float* __restrict__ P,
                                               const float* __restrict__ w,
                                               float* __restrict__ X,
                                               float* __restrict__ wnorm)
{
  const int b = blockIdx.x;
  const int t = threadIdx.x;
  float wsum = 0.0f;
  for (int n = 0; n < N_; ++n) wsum += w[n];
  const float inv = 1.0f / wsum;
  float4 acc = make_float4(0.f, 0.f, 0.f, 0.f);
  for (int n = 0; n < N_; ++n) {
    const float wn = w[n] * inv;
    const float4 p = *(const float4*)(P + ((size_t)(b*N_ + n))*DD*DD + t*4);
    acc.x += wn*p.x; acc.y += wn*p.y; acc.z += wn*p.z; acc.w += wn*p.w;
  }
  *(float4*)(X + (size_t)b*DD*DD + t*4) = acc;
  if (b == 0 && t < N_) wnorm[t] = w[t] * inv;
}

// ---------------------------------------------------------------------------
// prep: eigh(X) -> sq = X^{1/2}, isq = X^{-1/2}
// ---------------------------------------------------------------------------
__global__ __launch_bounds__(NT) void kern_prep(const float* __restrict__ Xin,
                                                float* __restrict__ sq,
                                                float* __restrict__ isq)
{
  __shared__ __align__(16) float S1a[NG][DD*LDM];
  __shared__ __align__(16) float csa[NG][DD];
  __shared__ __align__(16) float e0a[NG][DD];
  __shared__ __align__(16) float e1a[NG][DD];

  const int g  = threadIdx.x >> 5;
  const int lt = threadIdx.x & 31;
  const int b  = blockIdx.x * NG + g;
  float* S1 = S1a[g];

  float ind_[DD];
  #pragma unroll
  for (int i = 0; i < DD; ++i) ind_[i] = (i == lt) ? 1.0f : 0.0f;

  v2f a[DD/2], v[DD/2];
  float dg = 0.f;
  #pragma unroll
  for (int i = 0; i < DD; ++i) {
    const float val = Xin[(size_t)b*DD*DD + i*DD + lt];
    AE(i) = val;
    dg = fmaf(ind_[i], val, dg);
  }
  jacobi_xor<SW_MEAN>(a, v, ind_, dg, csa[g], lt);

  const float se = fast_sqrt(fmaxf(dg, EPS_));
  e0a[g][lt] = se;
  e1a[g][lt] = fast_rcp(se);
  #pragma unroll
  for (int i = 0; i < DD; ++i) S1[i*LDM + lt] = VE(i);
  wsync();

  float w1[DD], w2[DD];
  #pragma unroll
  for (int j = 0; j < 8; ++j) {
    const float4 vr = *(const float4*)(S1 + lt*LDM + 4*j);
    const float4 q0 = *(const float4*)(e0a[g] + 4*j);
    const float4 q1 = *(const float4*)(e1a[g] + 4*j);
    w1[4*j+0]=vr.x*q0.x; w1[4*j+1]=vr.y*q0.y; w1[4*j+2]=vr.z*q0.z; w1[4*j+3]=vr.w*q0.w;
    w2[4*j+0]=vr.x*q1.x; w2[4*j+1]=vr.y*q1.y; w2[4*j+2]=vr.z*q1.z; w2[4*j+3]=vr.w*q1.w;
  }
  #pragma unroll
  for (int i = 0; i < DD; ++i) {
    float a1 = 0.f, a2 = 0.f;
    #pragma unroll
    for (int j = 0; j < 8; ++j) {
      const float4 vk = *(const float4*)(S1 + i*LDM + 4*j);
      a1 += vk.x*w1[4*j+0] + vk.y*w1[4*j+1] + vk.z*w1[4*j+2] + vk.w*w1[4*j+3];
      a2 += vk.x*w2[4*j+0] + vk.y*w2[4*j+1] + vk.z*w2[4*j+2] + vk.w*w2[4*j+3];
    }
    sq [(size_t)b*DD*DD + i*DD + lt] = a1;
    isq[(size_t)b*DD*DD + i*DD + lt] = a2;
  }
}

// ---------------------------------------------------------------------------
// acc (NG=16, dynamic LDS): M = isq P isq (sym), eigh(M), L = V log(e) V^T,
// partial T -> part. LDS layout: qsh | S1a[16] | csa[16] (lga aliases csa).
// ---------------------------------------------------------------------------
__global__ __launch_bounds__(ACC_NT) void kern_acc(const float* __restrict__ P,
                                                   const float* __restrict__ wnorm,
                                                   const float* __restrict__ isq,
                                                   float* __restrict__ part)
{
  extern __shared__ __align__(16) float smem[];
  float* qsh = smem;                               // DD*LDM floats
  float* S1a = smem + DD*LDM;                      // ACC_NG * DD*LDM
  float* csa = S1a + (size_t)ACC_NG*DD*LDM;        // ACC_NG * DD

  const int g  = threadIdx.x >> 5;
  const int lt = threadIdx.x & 31;
  const int b  = blockIdx.x / PARTS;
  const int n  = (blockIdx.x % PARTS) * ACC_NG + g;
  float* S1 = S1a + (size_t)g*DD*LDM;
  float* cs = csa + g*DD;                          // also lga after jacobi

  for (int e = threadIdx.x; e < DD*DD; e += ACC_NT)
    qsh[(e >> 5)*LDM + (e & 31)] = isq[(size_t)b*DD*DD + e];

  const float* Pn = P + ((size_t)(b*N_ + n))*DD*DD;
  #pragma unroll
  for (int i = 0; i < DD; ++i) S1[i*LDM + lt] = Pn[i*DD + lt];  // stage P rows
  __syncthreads();

  float ind_[DD];
  #pragma unroll
  for (int i = 0; i < DD; ++i) ind_[i] = (i == lt) ? 1.0f : 0.0f;

  float qc[DD];                                   // isq column lt
  #pragma unroll
  for (int k = 0; k < DD; ++k) qc[k] = qsh[k*LDM + lt];
  // u = P * qc
  float u[DD];
  #pragma unroll
  for (int i = 0; i < DD; ++i) {
    float acc = 0.f;
    #pragma unroll
    for (int j = 0; j < 8; ++j) {
      const float4 pr = *(const float4*)(S1 + i*LDM + 4*j);
      acc += pr.x*qc[4*j+0] + pr.y*qc[4*j+1] + pr.z*qc[4*j+2] + pr.w*qc[4*j+3];
    }
    u[i] = acc;
  }
  // m-col = isq * u (= column lt of M)
  float mm[DD];
  #pragma unroll
  for (int i = 0; i < DD; ++i) {
    float acc = 0.f;
    #pragma unroll
    for (int j = 0; j < 8; ++j) {
      const float4 qr = *(const float4*)(qsh + i*LDM + 4*j);
      acc += qr.x*u[4*j+0] + qr.y*u[4*j+1] + qr.z*u[4*j+2] + qr.w*u[4*j+3];
    }
    mm[i] = acc;
  }
  // symmetrize via S1 (P no longer needed)
  wsync();
  #pragma unroll
  for (int i = 0; i < DD; ++i) S1[i*LDM + lt] = mm[i];
  wsync();
  v2f a[DD/2], v[DD/2];
  float dg = 0.f;
  #pragma unroll
  for (int i = 0; i < DD; ++i) {
    const float val = 0.5f*(mm[i] + S1[lt*LDM + i]);
    AE(i) = val;
    dg = fmaf(ind_[i], val, dg);
  }

  jacobi_xor<SW_ACC>(a, v, ind_, dg, cs, lt);

  cs[lt] = logf(fmaxf(dg, EPS_));   // lga aliased onto csa (jacobi done)
  wsync();
  #pragma unroll
  for (int i = 0; i < DD; ++i) S1[i*LDM + lt] = VE(i);   // spill V
  wsync();

  float wl[DD];
  #pragma unroll
  for (int j = 0; j < 8; ++j) {
    const float4 vr = *(const float4*)(S1 + lt*LDM + 4*j);
    const float4 l4 = *(const float4*)(cs + 4*j);
    wl[4*j+0]=vr.x*l4.x; wl[4*j+1]=vr.y*l4.y; wl[4*j+2]=vr.z*l4.z; wl[4*j+3]=vr.w*l4.w;
  }
  float tc[DD];
  #pragma unroll
  for (int i = 0; i < DD; ++i) {
    float acc = 0.f;
    #pragma unroll
    for (int j = 0; j < 8; ++j) {
      const float4 vk = *(const float4*)(S1 + i*LDM + 4*j);
      acc += vk.x*wl[4*j+0] + vk.y*wl[4*j+1] + vk.z*wl[4*j+2] + vk.w*wl[4*j+3];
    }
    tc[i] = acc;
  }
  const float wn = wnorm[n];
  wsync();
  #pragma unroll
  for (int i = 0; i < DD; ++i) S1[i*LDM + lt] = wn * tc[i];
  __syncthreads();
  // deterministic per-block partial (16 groups summed)
  for (int e = threadIdx.x; e < DD*DD; e += ACC_NT) {
    float ssum = 0.f;
    #pragma unroll
    for (int gg = 0; gg < ACC_NG; ++gg) ssum += S1a[(size_t)gg*DD*LDM + (e >> 5)*LDM + (e & 31)];
    part[(size_t)blockIdx.x*DD*DD + e] = ssum;
  }
}

// ---------------------------------------------------------------------------
// reduce: T[b] = 0.5*(S + S^T), S = sum_ps part[b*PARTS+ps]
// ---------------------------------------------------------------------------
__global__ __launch_bounds__(256) void kern_reduce(const float* __restrict__ part,
                                                   float* __restrict__ T)
{
  __shared__ float tile[DD*LDD];
  const int b = blockIdx.x, t = threadIdx.x;
  #pragma unroll
  for (int j = 0; j < 4; ++j) {
    const int e = t + 256*j;
    float s = 0.f;
    #pragma unroll
    for (int ps = 0; ps < PARTS; ++ps)
      s += part[((size_t)(b*PARTS + ps))*DD*DD + e];
    tile[(e >> 5)*LDD + (e & 31)] = s;
  }
  __syncthreads();
  #pragma unroll
  for (int j = 0; j < 4; ++j) {
    const int e = t + 256*j, i = e >> 5, k = e & 31;
    T[(size_t)b*DD*DD + e] = 0.5f*(tile[i*LDD + k] + tile[k*LDD + i]);
  }
}

// ---------------------------------------------------------------------------
// stepfuse: eigh(T), E=V exp(e) V^T, Xn = sq E sq (sym); then fused prep:
// eigh(Xn) -> sq', isq'. Last iteration writes Xn to out instead.
// ---------------------------------------------------------------------------
__global__ __launch_bounds__(NT) void kern_stepfuse(const float* __restrict__ T,
                                                    float* __restrict__ sq,
                                                    float* __restrict__ isq,
                                                    float* __restrict__ out,
                                                    const int last)
{
  __shared__ __align__(16) float S1a[NG][DD*LDM];
  __shared__ __align__(16) float S2a[NG][DD*LDM];
  __shared__ __align__(16) float csa[NG][DD];
  __shared__ __align__(16) float e0a[NG][DD];
  __shared__ __align__(16) float e1a[NG][DD];

  const int g  = threadIdx.x >> 5;
  const int lt = threadIdx.x & 31;
  const int b  = blockIdx.x * NG + g;
  float* S1 = S1a[g]; float* S2 = S2a[g];

  float ind_[DD];
  #pragma unroll
  for (int i = 0; i < DD; ++i) ind_[i] = (i == lt) ? 1.0f : 0.0f;

  v2f a[DD/2], v[DD/2];
  float dg = 0.f;
  #pragma unroll
  for (int i = 0; i < DD; ++i) {
    const float val = T[(size_t)b*DD*DD + i*DD + lt];   // T pre-symmetrized
    AE(i) = val;
    dg = fmaf(ind_[i], val, dg);
  }
  jacobi_xor<SW_MEAN>(a, v, ind_, dg, csa[g], lt);

  // E = V exp(d) V^T, column lt
  e0a[g][lt] = expf(dg);
  #pragma unroll
  for (int i = 0; i < DD; ++i) S1[i*LDM + lt] = VE(i);
  wsync();
  float wl[DD];
  #pragma unroll
  for (int j = 0; j < 8; ++j) {
    const float4 vr = *(const float4*)(S1 + lt*LDM + 4*j);
    const float4 ee = *(const float4*)(e0a[g] + 4*j);
    wl[4*j+0]=vr.x*ee.x; wl[4*j+1]=vr.y*ee.y; wl[4*j+2]=vr.z*ee.z; wl[4*j+3]=vr.w*ee.w;
  }
  float ec[DD];
  #pragma unroll
  for (int i = 0; i < DD; ++i) {
    float acc = 0.f;
    #pragma unroll
    for (int j = 0; j < 8; ++j) {
      const float4 vk = *(const float4*)(S1 + i*LDM + 4*j);
      acc += vk.x*wl[4*j+0] + vk.y*wl[4*j+1] + vk.z*wl[4*j+2] + vk.w*wl[4*j+3];
    }
    ec[i] = acc;
  }
  // stage sq rows (S2) + own column (sqc)
  float sqc[DD];
  #pragma unroll
  for (int i = 0; i < DD; ++i) {
    sqc[i] = sq[(size_t)b*DD*DD + i*DD + lt];
    S2[i*LDM + lt] = sqc[i];
  }
  wsync();
  #pragma unroll
  for (int i = 0; i < DD; ++i) S1[i*LDM + lt] = ec[i];  // E columns (V dead)
  wsync();
  // h = E * sqc
  float h[DD];
  #pragma unroll
  for (int i = 0; i < DD; ++i) {
    float acc = 0.f;
    #pragma unroll
    for (int j = 0; j < 8; ++j) {
      const float4 er = *(const float4*)(S1 + i*LDM + 4*j);
      acc += er.x*sqc[4*j+0] + er.y*sqc[4*j+1] + er.z*sqc[4*j+2] + er.w*sqc[4*j+3];
    }
    h[i] = acc;
  }
  // xn = sq * h
  float xn[DD];
  #pragma unroll
  for (int i = 0; i < DD; ++i) {
    float acc = 0.f;
    #pragma unroll
    for (int j = 0; j < 8; ++j) {
      const float4 sr = *(const float4*)(S2 + i*LDM + 4*j);
      acc += sr.x*h[4*j+0] + sr.y*h[4*j+1] + sr.z*h[4*j+2] + sr.w*h[4*j+3];
    }
    xn[i] = acc;
  }
  // symmetrize Xn via S1
  wsync();
  #pragma unroll
  for (int i = 0; i < DD; ++i) S1[i*LDM + lt] = xn[i];
  wsync();
  dg = 0.f;
  #pragma unroll
  for (int i = 0; i < DD; ++i) {
    const float val = 0.5f*(xn[i] + S1[lt*LDM + i]);
    AE(i) = val;
    dg = fmaf(ind_[i], val, dg);
  }

  if (last) {
    #pragma unroll
    for (int i = 0; i < DD; ++i) out[(size_t)b*DD*DD + i*DD + lt] = AE(i);
    return;
  }

  // fused prep: eigh(Xn) -> sq', isq'
  jacobi_xor<SW_MEAN>(a, v, ind_, dg, csa[g], lt);
  const float se = fast_sqrt(fmaxf(dg, EPS_));
  e0a[g][lt] = se;
  e1a[g][lt] = fast_rcp(se);
  wsync();
  #pragma unroll
  for (int i = 0; i < DD; ++i) S1[i*LDM + lt] = VE(i);
  wsync();
  float w1[DD], w2[DD];
  #pragma unroll
  for (int j = 0; j < 8; ++j) {
    const float4 vr = *(const float4*)(S1 + lt*LDM + 4*j);
    const float4 q0 = *(const float4*)(e0a[g] + 4*j);
    const float4 q1 = *(const float4*)(e1a[g] + 4*j);
    w1[4*j+0]=vr.x*q0.x; w1[4*j+1]=vr.y*q0.y; w1[4*j+2]=vr.z*q0.z; w1[4*j+3]=vr.w*q0.w;
    w2[4*j+0]=vr.x*q1.x; w2[4*j+1]=vr.y*q1.y; w2[4*j+2]=vr.z*q1.z; w2[4*j+3]=vr.w*q1.w;
  }
  #pragma unroll
  for (int i = 0; i < DD; ++i) {
    float a1 = 0.f, a2 = 0.f;
    #pragma unroll
    for (int j = 0; j < 8; ++j) {
      const float4 vk = *(const float4*)(S1 + i*LDM + 4*j);
      a1 += vk.x*w1[4*j+0] + vk.y*w1[4*j+1] + vk.z*w1[4*j+2] + vk.w*w1[4*j+3];
      a2 += vk.x*w2[4*j+0] + vk.y*w2[4*j+1] + vk.z*w2[4*j+2] + vk.w*w2[4*j+3];
    }
    sq [(size_t)b*DD*DD + i*DD + lt] = a1;
    isq[(size_t)b*DD*DD + i*DD + lt] = a2;
  }
}

// ---------------------------------------------------------------------------
extern "C" void kernel_launch(void* const* d_in, const int* in_sizes, int n_in,
                              void* d_out, int out_size, void* d_ws, size_t ws_size,
                              hipStream_t stream)
{
  (void)in_sizes; (void)n_in; (void)out_size; (void)ws_size;
  const float* P = (const float*)d_in[0];   // [B][N][32][32] f32
  const float* w = (const float*)d_in[1];   // [N] f32
  float* out   = (float*)d_out;
  float* T     = (float*)d_ws;                                  // 1 MB
  float* sq    = T   + (size_t)B_*DD*DD;                        // 1 MB
  float* isq   = sq  + (size_t)B_*DD*DD;                        // 1 MB
  float* part  = isq + (size_t)B_*DD*DD;                        // 4 MB
  float* wnorm = part + (size_t)B_*PARTS*DD*DD;                 // 256 B

  const size_t acc_lds = (size_t)(DD*LDM*(1 + ACC_NG) + ACC_NG*DD) * sizeof(float); // 80384 B

  kern_x0<<<B_, 256, 0, stream>>>(P, w, T, wnorm);
  kern_prep<<<B_/NG, NT, 0, stream>>>(T, sq, isq);
  for (int it = 0; it < ITERS; ++it) {
    kern_acc   <<<B_*PARTS, ACC_NT, acc_lds, stream>>>(P, wnorm, isq, part);
    kern_reduce<<<B_,       256, 0, stream>>>(part, T);
    kern_stepfuse<<<B_/NG,  NT,  0, stream>>>(T, sq, isq, out, (it == ITERS-1) ? 1 : 0);
  }
}